// Round 1
// baseline (2824.383 us; speedup 1.0000x reference)
//
#include <hip/hip_runtime.h>
#include <cstdint>

#define E_DIM   1024
#define NHEADS  16
#define HDIM    64
#define BATCHN  2
#define SEQLEN  2048
#define QKV_DIM 3072

// C[M,N] = A[M,K] @ W[N,K]^T + bias[N]
// A row-major [M,K], W row-major [N,K] (dot of rows -> both coalesced on K).
// 64x64 output tile, BK=16, 256 threads, 4x4 microtile per thread.
__global__ __launch_bounds__(256) void gemm_bias_kernel(
    const float* __restrict__ A, const float* __restrict__ W,
    const float* __restrict__ bias, float* __restrict__ C,
    int M, int N, int K)
{
    // transposed tiles [k][row], pad row-length to 68 floats (16B-aligned rows,
    // 2-way-max bank aliasing which is free on CDNA4)
    __shared__ float As[16][68];
    __shared__ float Ws[16][68];
    const int bm = blockIdx.y * 64;
    const int bn = blockIdx.x * 64;
    const int tid = (int)threadIdx.x;
    const int tr = tid >> 4;   // 0..15 (row group)
    const int tc = tid & 15;   // 0..15 (col group)
    const int lrow = tid >> 2; // 0..63 (global-load row)
    const int lk4  = tid & 3;  // float4 index in 16-float K chunk

    const float4* A4 = (const float4*)A;
    const float4* W4 = (const float4*)W;
    const int K4 = K >> 2;

    float acc[4][4] = {};

    for (int k0 = 0; k0 < K; k0 += 16) {
        float4 av = A4[(size_t)(bm + lrow) * K4 + (k0 >> 2) + lk4];
        float4 wv = W4[(size_t)(bn + lrow) * K4 + (k0 >> 2) + lk4];
        As[lk4 * 4 + 0][lrow] = av.x;
        As[lk4 * 4 + 1][lrow] = av.y;
        As[lk4 * 4 + 2][lrow] = av.z;
        As[lk4 * 4 + 3][lrow] = av.w;
        Ws[lk4 * 4 + 0][lrow] = wv.x;
        Ws[lk4 * 4 + 1][lrow] = wv.y;
        Ws[lk4 * 4 + 2][lrow] = wv.z;
        Ws[lk4 * 4 + 3][lrow] = wv.w;
        __syncthreads();
        #pragma unroll
        for (int kk = 0; kk < 16; ++kk) {
            float4 a = *(const float4*)&As[kk][tr * 4];
            float4 b = *(const float4*)&Ws[kk][tc * 4];
            float av2[4] = {a.x, a.y, a.z, a.w};
            float bv2[4] = {b.x, b.y, b.z, b.w};
            #pragma unroll
            for (int i = 0; i < 4; ++i)
                #pragma unroll
                for (int j = 0; j < 4; ++j)
                    acc[i][j] = fmaf(av2[i], bv2[j], acc[i][j]);
        }
        __syncthreads();
    }

    const float4* bias4 = (const float4*)bias;
    float4 bv = bias4[(bn >> 2) + tc];
    #pragma unroll
    for (int i = 0; i < 4; ++i) {
        const int row = bm + tr * 4 + i;
        float4 o;
        o.x = acc[i][0] + bv.x;
        o.y = acc[i][1] + bv.y;
        o.z = acc[i][2] + bv.z;
        o.w = acc[i][3] + bv.w;
        *(float4*)&C[(size_t)row * N + bn + tc * 4] = o;
    }
}

// Flash-style attention, fp32. qkv: [B*S, 3E] rows (q | k | v). y: [B*S, E].
// One block per (query-block of 64, head, batch). 256 threads:
// 4 lanes per query row, each lane owns 16 key columns of the 64-key tile.
__global__ __launch_bounds__(256) void attn_kernel(
    const float* __restrict__ qkv, float* __restrict__ y)
{
    __shared__ float Qs[64][68];
    __shared__ float Ks[64][68];
    __shared__ float Vs[64][68];

    const int qb = blockIdx.x;
    const int h  = blockIdx.y;
    const int b  = blockIdx.z;
    const int tid = (int)threadIdx.x;
    const int row = tid >> 2;  // query row in block (0..63)
    const int cg  = tid & 3;   // column group (16 cols each)
    const float scale = 0.125f;  // 1/sqrt(64)

    const float4* qkv4 = (const float4*)qkv;
    const int RS4 = QKV_DIM / 4;  // 768 float4 per token row

    // load Q tile [64][64]
    {
        const size_t base = (size_t)(b * SEQLEN + qb * 64) * RS4 + (h * HDIM) / 4;
        #pragma unroll
        for (int p = 0; p < 4; ++p) {
            int idx = p * 256 + tid;
            int r = idx >> 4, d4 = idx & 15;
            float4 v = qkv4[base + (size_t)r * RS4 + d4];
            *(float4*)&Qs[r][d4 * 4] = v;
        }
    }

    float m_run = -1e30f, l_run = 0.f;
    float4 acc[16];
    #pragma unroll
    for (int i = 0; i < 16; ++i) acc[i] = make_float4(0.f, 0.f, 0.f, 0.f);

    for (int kt = 0; kt < SEQLEN / 64; ++kt) {
        __syncthreads();  // previous-iter LDS reads done before overwrite
        const size_t kb = (size_t)(b * SEQLEN + kt * 64) * RS4 + (E_DIM + h * HDIM) / 4;
        const size_t vb = (size_t)(b * SEQLEN + kt * 64) * RS4 + (2 * E_DIM + h * HDIM) / 4;
        #pragma unroll
        for (int p = 0; p < 4; ++p) {
            int idx = p * 256 + tid;
            int r = idx >> 4, d4 = idx & 15;
            *(float4*)&Ks[r][d4 * 4] = qkv4[kb + (size_t)r * RS4 + d4];
            *(float4*)&Vs[r][d4 * 4] = qkv4[vb + (size_t)r * RS4 + d4];
        }
        __syncthreads();

        // scores: s[jj] = scale * Q[row] . K[cg*16+jj]
        float s[16];
        #pragma unroll
        for (int jj = 0; jj < 16; ++jj) s[jj] = 0.f;
        #pragma unroll
        for (int d4 = 0; d4 < 16; ++d4) {
            float4 q = *(const float4*)&Qs[row][d4 * 4];
            #pragma unroll
            for (int jj = 0; jj < 16; ++jj) {
                float4 k = *(const float4*)&Ks[cg * 16 + jj][d4 * 4];
                s[jj] = fmaf(q.x, k.x, fmaf(q.y, k.y, fmaf(q.z, k.z, fmaf(q.w, k.w, s[jj]))));
            }
        }

        float mt = -1e30f;
        #pragma unroll
        for (int jj = 0; jj < 16; ++jj) { s[jj] *= scale; mt = fmaxf(mt, s[jj]); }
        mt = fmaxf(mt, __shfl_xor(mt, 1));
        mt = fmaxf(mt, __shfl_xor(mt, 2));
        const float m_new = fmaxf(m_run, mt);
        const float corr = __expf(m_run - m_new);

        float p[16];
        float lt = 0.f;
        #pragma unroll
        for (int jj = 0; jj < 16; ++jj) { p[jj] = __expf(s[jj] - m_new); lt += p[jj]; }
        lt += __shfl_xor(lt, 1);
        lt += __shfl_xor(lt, 2);
        l_run = l_run * corr + lt;
        m_run = m_new;

        #pragma unroll
        for (int d4 = 0; d4 < 16; ++d4) {
            acc[d4].x *= corr; acc[d4].y *= corr;
            acc[d4].z *= corr; acc[d4].w *= corr;
        }
        #pragma unroll
        for (int jj = 0; jj < 16; ++jj) {
            const float pv = p[jj];
            #pragma unroll
            for (int d4 = 0; d4 < 16; ++d4) {
                float4 v = *(const float4*)&Vs[cg * 16 + jj][d4 * 4];
                acc[d4].x = fmaf(pv, v.x, acc[d4].x);
                acc[d4].y = fmaf(pv, v.y, acc[d4].y);
                acc[d4].z = fmaf(pv, v.z, acc[d4].z);
                acc[d4].w = fmaf(pv, v.w, acc[d4].w);
            }
        }
    }

    // combine the 4 column-group partials per row (lanes row*4 .. row*4+3)
    #pragma unroll
    for (int d4 = 0; d4 < 16; ++d4) {
        acc[d4].x += __shfl_xor(acc[d4].x, 1);
        acc[d4].x += __shfl_xor(acc[d4].x, 2);
        acc[d4].y += __shfl_xor(acc[d4].y, 1);
        acc[d4].y += __shfl_xor(acc[d4].y, 2);
        acc[d4].z += __shfl_xor(acc[d4].z, 1);
        acc[d4].z += __shfl_xor(acc[d4].z, 2);
        acc[d4].w += __shfl_xor(acc[d4].w, 1);
        acc[d4].w += __shfl_xor(acc[d4].w, 2);
    }
    const float inv_l = 1.f / l_run;
    float* yrow = y + (size_t)(b * SEQLEN + qb * 64 + row) * E_DIM + h * HDIM;
    #pragma unroll
    for (int q4 = 0; q4 < 4; ++q4) {
        const int d4 = cg * 4 + q4;
        float4 o = acc[d4];
        o.x *= inv_l; o.y *= inv_l; o.z *= inv_l; o.w *= inv_l;
        *(float4*)&yrow[d4 * 4] = o;
    }
}

extern "C" void kernel_launch(void* const* d_in, const int* in_sizes, int n_in,
                              void* d_out, int out_size, void* d_ws, size_t ws_size,
                              hipStream_t stream)
{
    const float* x    = (const float*)d_in[0];
    const float* win  = (const float*)d_in[1];
    const float* bin  = (const float*)d_in[2];
    const float* wout = (const float*)d_in[3];
    const float* bout = (const float*)d_in[4];
    float* out = (float*)d_out;

    float* qkv = (float*)d_ws;                                  // [4096, 3072] f32
    float* yat = qkv + (size_t)BATCHN * SEQLEN * QKV_DIM;       // [4096, 1024] f32

    const int M = BATCHN * SEQLEN;  // 4096
    dim3 blk(256);

    // 1) qkv = x @ Win^T + bin
    gemm_bias_kernel<<<dim3(QKV_DIM / 64, M / 64), blk, 0, stream>>>(
        x, win, bin, qkv, M, QKV_DIM, E_DIM);

    // 2) streaming attention per (qblock, head, batch)
    attn_kernel<<<dim3(SEQLEN / 64, NHEADS, BATCHN), blk, 0, stream>>>(qkv, yat);

    // 3) out = yat @ Wout^T + bout
    gemm_bias_kernel<<<dim3(E_DIM / 64, M / 64), blk, 0, stream>>>(
        yat, wout, bout, out, M, E_DIM, E_DIM);
}

// Round 2
// 570.699 us; speedup vs baseline: 4.9490x; 4.9490x over previous
//
#include <hip/hip_runtime.h>
#include <hip/hip_bf16.h>
#include <cstdint>

#define E_DIM   1024
#define NHEADS  16
#define HDIM    64
#define BATCHN  2
#define SEQLEN  2048
#define QKV_DIM 3072

typedef __attribute__((ext_vector_type(8))) short bf16x8;
typedef __attribute__((ext_vector_type(4))) float f32x4;

__device__ inline short f2bf_raw(float v) {
    __hip_bfloat16 t = __float2bfloat16(v);
    return *reinterpret_cast<short*>(&t);
}

// ---------------------------------------------------------------------------
// GEMM1: qkv = x @ Win^T + bin, fused epilogue writes bf16:
//   q_buf[b][h][s][d], k_buf[b][h][s][d], vT_buf[b][h][d][s]
// fp32 compute, 64x64 tile, BK=16, 256 threads, 4x4 microtile.
// ---------------------------------------------------------------------------
__global__ __launch_bounds__(256) void gemm_qkv_kernel(
    const float* __restrict__ A, const float* __restrict__ W,
    const float* __restrict__ bias,
    __hip_bfloat16* __restrict__ qbuf, __hip_bfloat16* __restrict__ kbuf,
    __hip_bfloat16* __restrict__ vtbuf)
{
    __shared__ float As[16][68];
    __shared__ float Ws[16][68];
    const int K = E_DIM;            // 1024
    const int bm = blockIdx.y * 64;
    const int bn = blockIdx.x * 64;
    const int tid = (int)threadIdx.x;
    const int tr = tid >> 4;
    const int tc = tid & 15;
    const int lrow = tid >> 2;
    const int lk4  = tid & 3;

    const float4* A4 = (const float4*)A;
    const float4* W4 = (const float4*)W;
    const int K4 = K >> 2;

    float acc[4][4] = {};

    for (int k0 = 0; k0 < K; k0 += 16) {
        float4 av = A4[(size_t)(bm + lrow) * K4 + (k0 >> 2) + lk4];
        float4 wv = W4[(size_t)(bn + lrow) * K4 + (k0 >> 2) + lk4];
        As[lk4 * 4 + 0][lrow] = av.x;
        As[lk4 * 4 + 1][lrow] = av.y;
        As[lk4 * 4 + 2][lrow] = av.z;
        As[lk4 * 4 + 3][lrow] = av.w;
        Ws[lk4 * 4 + 0][lrow] = wv.x;
        Ws[lk4 * 4 + 1][lrow] = wv.y;
        Ws[lk4 * 4 + 2][lrow] = wv.z;
        Ws[lk4 * 4 + 3][lrow] = wv.w;
        __syncthreads();
        #pragma unroll
        for (int kk = 0; kk < 16; ++kk) {
            float4 a = *(const float4*)&As[kk][tr * 4];
            float4 b = *(const float4*)&Ws[kk][tc * 4];
            float av2[4] = {a.x, a.y, a.z, a.w};
            float bv2[4] = {b.x, b.y, b.z, b.w};
            #pragma unroll
            for (int i = 0; i < 4; ++i)
                #pragma unroll
                for (int j = 0; j < 4; ++j)
                    acc[i][j] = fmaf(av2[i], bv2[j], acc[i][j]);
        }
        __syncthreads();
    }

    const float4* bias4 = (const float4*)bias;
    const int n0 = bn + tc * 4;
    float4 bv = bias4[n0 >> 2];
    const int region = n0 >> 10;        // 0=q 1=k 2=v
    const int h  = (n0 >> 6) & 15;
    const int d0 = n0 & 63;

    #pragma unroll
    for (int i = 0; i < 4; ++i) {
        const int row = bm + tr * 4 + i;
        const int bb = row >> 11;       // batch
        const int s  = row & 2047;      // seq pos
        float v0 = acc[i][0] + bv.x;
        float v1 = acc[i][1] + bv.y;
        float v2 = acc[i][2] + bv.z;
        float v3 = acc[i][3] + bv.w;
        if (region == 2) {
            // vT[b][h][d][s]
            __hip_bfloat16* base = vtbuf + ((size_t)(bb * NHEADS + h) * HDIM) * SEQLEN + s;
            base[(size_t)(d0 + 0) * SEQLEN] = __float2bfloat16(v0);
            base[(size_t)(d0 + 1) * SEQLEN] = __float2bfloat16(v1);
            base[(size_t)(d0 + 2) * SEQLEN] = __float2bfloat16(v2);
            base[(size_t)(d0 + 3) * SEQLEN] = __float2bfloat16(v3);
        } else {
            __hip_bfloat16* dst = (region == 0 ? qbuf : kbuf)
                + ((size_t)(bb * NHEADS + h) * SEQLEN + s) * HDIM + d0;
            short4 pk;
            pk.x = f2bf_raw(v0); pk.y = f2bf_raw(v1);
            pk.z = f2bf_raw(v2); pk.w = f2bf_raw(v3);
            *(short4*)dst = pk;
        }
    }
}

// ---------------------------------------------------------------------------
// GEMM2 (out-proj): C = A @ W^T + bias, fp32 (as round 1).
// ---------------------------------------------------------------------------
__global__ __launch_bounds__(256) void gemm_bias_kernel(
    const float* __restrict__ A, const float* __restrict__ W,
    const float* __restrict__ bias, float* __restrict__ C,
    int M, int N, int K)
{
    __shared__ float As[16][68];
    __shared__ float Ws[16][68];
    const int bm = blockIdx.y * 64;
    const int bn = blockIdx.x * 64;
    const int tid = (int)threadIdx.x;
    const int tr = tid >> 4;
    const int tc = tid & 15;
    const int lrow = tid >> 2;
    const int lk4  = tid & 3;

    const float4* A4 = (const float4*)A;
    const float4* W4 = (const float4*)W;
    const int K4 = K >> 2;

    float acc[4][4] = {};

    for (int k0 = 0; k0 < K; k0 += 16) {
        float4 av = A4[(size_t)(bm + lrow) * K4 + (k0 >> 2) + lk4];
        float4 wv = W4[(size_t)(bn + lrow) * K4 + (k0 >> 2) + lk4];
        As[lk4 * 4 + 0][lrow] = av.x;
        As[lk4 * 4 + 1][lrow] = av.y;
        As[lk4 * 4 + 2][lrow] = av.z;
        As[lk4 * 4 + 3][lrow] = av.w;
        Ws[lk4 * 4 + 0][lrow] = wv.x;
        Ws[lk4 * 4 + 1][lrow] = wv.y;
        Ws[lk4 * 4 + 2][lrow] = wv.z;
        Ws[lk4 * 4 + 3][lrow] = wv.w;
        __syncthreads();
        #pragma unroll
        for (int kk = 0; kk < 16; ++kk) {
            float4 a = *(const float4*)&As[kk][tr * 4];
            float4 b = *(const float4*)&Ws[kk][tc * 4];
            float av2[4] = {a.x, a.y, a.z, a.w};
            float bv2[4] = {b.x, b.y, b.z, b.w};
            #pragma unroll
            for (int i = 0; i < 4; ++i)
                #pragma unroll
                for (int j = 0; j < 4; ++j)
                    acc[i][j] = fmaf(av2[i], bv2[j], acc[i][j]);
        }
        __syncthreads();
    }

    const float4* bias4 = (const float4*)bias;
    float4 bv = bias4[(bn >> 2) + tc];
    #pragma unroll
    for (int i = 0; i < 4; ++i) {
        const int row = bm + tr * 4 + i;
        float4 o;
        o.x = acc[i][0] + bv.x;
        o.y = acc[i][1] + bv.y;
        o.z = acc[i][2] + bv.z;
        o.w = acc[i][3] + bv.w;
        *(float4*)&C[(size_t)row * N + bn + tc * 4] = o;
    }
}

// ---------------------------------------------------------------------------
// Flash attention, bf16 MFMA (16x16x32), fp32 accumulate.
// Grid: (S/64, H, B). Block: 256 = 4 waves; wave w owns q-rows w*16..w*16+15.
// K tile 64 keys. Online softmax in C-fragment registers.
// ---------------------------------------------------------------------------
__global__ __launch_bounds__(256) void attn_mfma_kernel(
    const __hip_bfloat16* __restrict__ qb, const __hip_bfloat16* __restrict__ kb,
    const __hip_bfloat16* __restrict__ vtb, float* __restrict__ y)
{
    __shared__ __hip_bfloat16 Klds[64][72];    // [key][d]
    __shared__ __hip_bfloat16 Vtlds[64][72];   // [d][key]
    __shared__ __hip_bfloat16 Plds[4][16][72]; // per-wave [q][key]

    const int qblk = blockIdx.x;
    const int h = blockIdx.y;
    const int b = blockIdx.z;
    const int bh = b * NHEADS + h;
    const int tid = (int)threadIdx.x;
    const int wv = tid >> 6;
    const int lane = tid & 63;
    const int lr = lane & 15;   // fragment row/col index
    const int lg = lane >> 4;   // 0..3
    const float scale = 0.125f;

    // Q fragments in registers: A[q=lr][d = ks*32 + lg*8 + j]
    const __hip_bfloat16* qrow =
        qb + ((size_t)bh * SEQLEN + qblk * 64 + wv * 16 + lr) * HDIM;
    bf16x8 qfrag0 = *(const bf16x8*)(qrow + lg * 8);
    bf16x8 qfrag1 = *(const bf16x8*)(qrow + 32 + lg * 8);

    f32x4 o[4];
    #pragma unroll
    for (int dt = 0; dt < 4; ++dt) o[dt] = (f32x4){0.f, 0.f, 0.f, 0.f};
    float m_run[4], l_run[4];
    #pragma unroll
    for (int r = 0; r < 4; ++r) { m_run[r] = -1e30f; l_run[r] = 0.f; }

    const __hip_bfloat16* kbase  = kb  + (size_t)bh * SEQLEN * HDIM;
    const __hip_bfloat16* vtbase = vtb + (size_t)bh * HDIM * SEQLEN;

    for (int kt = 0; kt < SEQLEN / 64; ++kt) {
        __syncthreads();
        #pragma unroll
        for (int p = 0; p < 2; ++p) {
            int idx = p * 256 + tid;
            int r = idx >> 3, c8 = (idx & 7) * 8;
            *(bf16x8*)&Klds[r][c8] =
                *(const bf16x8*)(kbase + (size_t)(kt * 64 + r) * HDIM + c8);
            *(bf16x8*)&Vtlds[r][c8] =
                *(const bf16x8*)(vtbase + (size_t)r * SEQLEN + kt * 64 + c8);
        }
        __syncthreads();

        // S[q][key] per wave: 4 key-tiles x 2 k-steps
        f32x4 s[4];
        #pragma unroll
        for (int t = 0; t < 4; ++t) s[t] = (f32x4){0.f, 0.f, 0.f, 0.f};
        #pragma unroll
        for (int t = 0; t < 4; ++t) {
            bf16x8 kf0 = *(const bf16x8*)&Klds[t * 16 + lr][lg * 8];
            bf16x8 kf1 = *(const bf16x8*)&Klds[t * 16 + lr][32 + lg * 8];
            s[t] = __builtin_amdgcn_mfma_f32_16x16x32_bf16(qfrag0, kf0, s[t], 0, 0, 0);
            s[t] = __builtin_amdgcn_mfma_f32_16x16x32_bf16(qfrag1, kf1, s[t], 0, 0, 0);
        }

        // online softmax: lane holds S[q = lg*4 + r][key = t*16 + lr]
        #pragma unroll
        for (int r = 0; r < 4; ++r) {
            float s0 = s[0][r] * scale, s1 = s[1][r] * scale;
            float s2 = s[2][r] * scale, s3 = s[3][r] * scale;
            float mr = fmaxf(fmaxf(s0, s1), fmaxf(s2, s3));
            mr = fmaxf(mr, __shfl_xor(mr, 1));
            mr = fmaxf(mr, __shfl_xor(mr, 2));
            mr = fmaxf(mr, __shfl_xor(mr, 4));
            mr = fmaxf(mr, __shfl_xor(mr, 8));
            const float mnew = fmaxf(m_run[r], mr);
            const float corr = __expf(m_run[r] - mnew);
            m_run[r] = mnew;
            s0 = __expf(s0 - mnew); s1 = __expf(s1 - mnew);
            s2 = __expf(s2 - mnew); s3 = __expf(s3 - mnew);
            float ls = s0 + s1 + s2 + s3;
            ls += __shfl_xor(ls, 1);
            ls += __shfl_xor(ls, 2);
            ls += __shfl_xor(ls, 4);
            ls += __shfl_xor(ls, 8);
            l_run[r] = l_run[r] * corr + ls;
            #pragma unroll
            for (int dt = 0; dt < 4; ++dt) o[dt][r] *= corr;
            const int q = lg * 4 + r;
            Plds[wv][q][ 0 + lr] = __float2bfloat16(s0);
            Plds[wv][q][16 + lr] = __float2bfloat16(s1);
            Plds[wv][q][32 + lr] = __float2bfloat16(s2);
            Plds[wv][q][48 + lr] = __float2bfloat16(s3);
        }

        // PV: O += P @ V   (A[q=lr][key], B[key][d = dt*16+lr])
        #pragma unroll
        for (int ks = 0; ks < 2; ++ks) {
            bf16x8 pa = *(const bf16x8*)&Plds[wv][lr][ks * 32 + lg * 8];
            #pragma unroll
            for (int dt = 0; dt < 4; ++dt) {
                bf16x8 vf = *(const bf16x8*)&Vtlds[dt * 16 + lr][ks * 32 + lg * 8];
                o[dt] = __builtin_amdgcn_mfma_f32_16x16x32_bf16(pa, vf, o[dt], 0, 0, 0);
            }
        }
    }

    // epilogue: y[b][s][h*64 + d] = o / l
    #pragma unroll
    for (int r = 0; r < 4; ++r) {
        const float inv = 1.f / l_run[r];
        float* yr = y + ((size_t)b * SEQLEN + qblk * 64 + wv * 16 + lg * 4 + r) * E_DIM
                      + h * HDIM;
        #pragma unroll
        for (int dt = 0; dt < 4; ++dt)
            yr[dt * 16 + lr] = o[dt][r] * inv;
    }
}

extern "C" void kernel_launch(void* const* d_in, const int* in_sizes, int n_in,
                              void* d_out, int out_size, void* d_ws, size_t ws_size,
                              hipStream_t stream)
{
    const float* x    = (const float*)d_in[0];
    const float* win  = (const float*)d_in[1];
    const float* bin  = (const float*)d_in[2];
    const float* wout = (const float*)d_in[3];
    const float* bout = (const float*)d_in[4];
    float* out = (float*)d_out;

    const size_t per_buf = (size_t)BATCHN * NHEADS * SEQLEN * HDIM;  // 4.19M elems
    __hip_bfloat16* qbuf  = (__hip_bfloat16*)d_ws;
    __hip_bfloat16* kbuf  = qbuf + per_buf;
    __hip_bfloat16* vtbuf = kbuf + per_buf;
    float* yat = (float*)((char*)d_ws + 3 * per_buf * sizeof(__hip_bfloat16));

    const int M = BATCHN * SEQLEN;  // 4096
    dim3 blk(256);

    // 1) qkv projection -> bf16 q/k/vT buffers
    gemm_qkv_kernel<<<dim3(QKV_DIM / 64, M / 64), blk, 0, stream>>>(
        x, win, bin, qbuf, kbuf, vtbuf);

    // 2) bf16 MFMA flash attention
    attn_mfma_kernel<<<dim3(SEQLEN / 64, NHEADS, BATCHN), blk, 0, stream>>>(
        qbuf, kbuf, vtbuf, yat);

    // 3) out-proj fp32
    gemm_bias_kernel<<<dim3(E_DIM / 64, M / 64), blk, 0, stream>>>(
        yat, wout, bout, out, M, E_DIM, E_DIM);
}

// Round 3
// 219.483 us; speedup vs baseline: 12.8683x; 2.6002x over previous
//
#include <hip/hip_runtime.h>
#include <hip/hip_bf16.h>
#include <cstdint>

#define E_DIM   1024
#define NHEADS  16
#define HDIM    64
#define BATCHN  2
#define SEQLEN  2048
#define QKV_DIM 3072

typedef __attribute__((ext_vector_type(8))) short bf16x8;
typedef __attribute__((ext_vector_type(8))) short short8_t;
typedef __attribute__((ext_vector_type(4))) float f32x4;

__device__ __forceinline__ short f2bf_raw(float v) {
    __hip_bfloat16 t = __float2bfloat16(v);
    return *reinterpret_cast<short*>(&t);
}

__device__ __forceinline__ void gload_lds16(const __hip_bfloat16* g, __hip_bfloat16* l) {
    __builtin_amdgcn_global_load_lds(
        (const __attribute__((address_space(1))) uint32_t*)(const void*)g,
        (__attribute__((address_space(3))) uint32_t*)(void*)l,
        16, 0, 0);
}

// ---------------------------------------------------------------------------
// fp32 -> bf16 cast, 8 elems/thread
// ---------------------------------------------------------------------------
__global__ __launch_bounds__(256) void cast_kernel(
    const float* __restrict__ s, __hip_bfloat16* __restrict__ d, int n8)
{
    int i = blockIdx.x * 256 + (int)threadIdx.x;
    if (i >= n8) return;
    const float4* s4 = (const float4*)s;
    float4 a = s4[i * 2];
    float4 b = s4[i * 2 + 1];
    short8_t o;
    o[0] = f2bf_raw(a.x); o[1] = f2bf_raw(a.y);
    o[2] = f2bf_raw(a.z); o[3] = f2bf_raw(a.w);
    o[4] = f2bf_raw(b.x); o[5] = f2bf_raw(b.y);
    o[6] = f2bf_raw(b.z); o[7] = f2bf_raw(b.w);
    *(short8_t*)&d[(size_t)i * 8] = o;
}

// ---------------------------------------------------------------------------
// bf16 MFMA GEMM: C[M,N] = A[M,K] @ W[N,K]^T + bias
// 128x128 tile, BK=64, 256 threads (4 waves 2x2), 4x4 16x16 fragments/wave.
// Staging via global_load_lds width 16 (m97 structure, single LDS buffer).
// EPI=0: fp32 C + bias.  EPI=1: fused QKV split -> q/k row-major, vT, bf16.
// ---------------------------------------------------------------------------
template<int EPI>
__global__ __launch_bounds__(256) void gemm_bf16_kernel(
    const __hip_bfloat16* __restrict__ A, const __hip_bfloat16* __restrict__ W,
    const float* __restrict__ bias, float* __restrict__ C,
    __hip_bfloat16* __restrict__ qbuf, __hip_bfloat16* __restrict__ kbuf,
    __hip_bfloat16* __restrict__ vtbuf, int M, int N, int K)
{
    __shared__ __hip_bfloat16 As[128 * 64];
    __shared__ __hip_bfloat16 Ws[128 * 64];

    const int tid  = (int)threadIdx.x;
    const int wv   = tid >> 6;
    const int lane = tid & 63;
    const int lr   = lane & 15;
    const int lg   = lane >> 4;
    const int wr   = wv >> 1;
    const int wc   = wv & 1;

    const int bm = blockIdx.y * 128;
    const int bn = blockIdx.x * 128;

    const int srow = lane >> 3;        // 0..7 row within 8-row chunk
    const int sk   = (lane & 7) * 8;   // elem offset within 64-elem row

    f32x4 acc[4][4];
    #pragma unroll
    for (int m = 0; m < 4; ++m)
        #pragma unroll
        for (int n = 0; n < 4; ++n)
            acc[m][n] = (f32x4){0.f, 0.f, 0.f, 0.f};

    for (int k0 = 0; k0 < K; k0 += 64) {
        __syncthreads();
        #pragma unroll
        for (int i = 0; i < 4; ++i) {
            const int r = i * 32 + wv * 8;
            gload_lds16(A + (size_t)(bm + r + srow) * K + k0 + sk, &As[r * 64]);
            gload_lds16(W + (size_t)(bn + r + srow) * K + k0 + sk, &Ws[r * 64]);
        }
        __syncthreads();
        #pragma unroll
        for (int ks = 0; ks < 2; ++ks) {
            bf16x8 af[4], wf[4];
            #pragma unroll
            for (int m = 0; m < 4; ++m)
                af[m] = *(const bf16x8*)&As[(wr * 64 + m * 16 + lr) * 64 + ks * 32 + lg * 8];
            #pragma unroll
            for (int n = 0; n < 4; ++n)
                wf[n] = *(const bf16x8*)&Ws[(wc * 64 + n * 16 + lr) * 64 + ks * 32 + lg * 8];
            #pragma unroll
            for (int m = 0; m < 4; ++m)
                #pragma unroll
                for (int n = 0; n < 4; ++n)
                    acc[m][n] = __builtin_amdgcn_mfma_f32_16x16x32_bf16(
                        af[m], wf[n], acc[m][n], 0, 0, 0);
        }
    }

    if (EPI == 0) {
        #pragma unroll
        for (int n = 0; n < 4; ++n) {
            const int col = bn + wc * 64 + n * 16 + lr;
            const float bv = bias[col];
            #pragma unroll
            for (int m = 0; m < 4; ++m) {
                const int row0 = bm + wr * 64 + m * 16 + lg * 4;
                #pragma unroll
                for (int rr = 0; rr < 4; ++rr)
                    C[(size_t)(row0 + rr) * N + col] = acc[m][n][rr] + bv;
            }
        }
    } else {
        #pragma unroll
        for (int n = 0; n < 4; ++n) {
            const int col = bn + wc * 64 + n * 16 + lr;
            const float bv = bias[col];
            const int region = col >> 10;
            const int h = (col >> 6) & 15;
            const int d = col & 63;
            #pragma unroll
            for (int m = 0; m < 4; ++m) {
                #pragma unroll
                for (int rr = 0; rr < 4; ++rr) {
                    const int row = bm + wr * 64 + m * 16 + lg * 4 + rr;
                    const int bb = row >> 11;
                    const int s  = row & 2047;
                    const float v = acc[m][n][rr] + bv;
                    if (region == 2) {
                        vtbuf[((size_t)(bb * NHEADS + h) * HDIM + d) * SEQLEN + s] =
                            __float2bfloat16(v);
                    } else {
                        ((region == 0) ? qbuf : kbuf)
                            [((size_t)(bb * NHEADS + h) * SEQLEN + s) * HDIM + d] =
                            __float2bfloat16(v);
                    }
                }
            }
        }
    }
}

// ---------------------------------------------------------------------------
// Flash attention, bf16 MFMA (16x16x32), fp32 accumulate. Output bf16.
// Grid: (S/64, H, B). Block: 256 = 4 waves; wave w owns q-rows w*16..w*16+15.
// ---------------------------------------------------------------------------
__global__ __launch_bounds__(256) void attn_mfma_kernel(
    const __hip_bfloat16* __restrict__ qb, const __hip_bfloat16* __restrict__ kb,
    const __hip_bfloat16* __restrict__ vtb, __hip_bfloat16* __restrict__ y)
{
    __shared__ __hip_bfloat16 Klds[64][72];
    __shared__ __hip_bfloat16 Vtlds[64][72];
    __shared__ __hip_bfloat16 Plds[4][16][72];

    const int qblk = blockIdx.x;
    const int h = blockIdx.y;
    const int b = blockIdx.z;
    const int bh = b * NHEADS + h;
    const int tid = (int)threadIdx.x;
    const int wv = tid >> 6;
    const int lane = tid & 63;
    const int lr = lane & 15;
    const int lg = lane >> 4;
    const float scale = 0.125f;

    const __hip_bfloat16* qrow =
        qb + ((size_t)bh * SEQLEN + qblk * 64 + wv * 16 + lr) * HDIM;
    bf16x8 qfrag0 = *(const bf16x8*)(qrow + lg * 8);
    bf16x8 qfrag1 = *(const bf16x8*)(qrow + 32 + lg * 8);

    f32x4 o[4];
    #pragma unroll
    for (int dt = 0; dt < 4; ++dt) o[dt] = (f32x4){0.f, 0.f, 0.f, 0.f};
    float m_run[4], l_run[4];
    #pragma unroll
    for (int r = 0; r < 4; ++r) { m_run[r] = -1e30f; l_run[r] = 0.f; }

    const __hip_bfloat16* kbase  = kb  + (size_t)bh * SEQLEN * HDIM;
    const __hip_bfloat16* vtbase = vtb + (size_t)bh * HDIM * SEQLEN;

    for (int kt = 0; kt < SEQLEN / 64; ++kt) {
        __syncthreads();
        #pragma unroll
        for (int p = 0; p < 2; ++p) {
            int idx = p * 256 + tid;
            int r = idx >> 3, c8 = (idx & 7) * 8;
            *(bf16x8*)&Klds[r][c8] =
                *(const bf16x8*)(kbase + (size_t)(kt * 64 + r) * HDIM + c8);
            *(bf16x8*)&Vtlds[r][c8] =
                *(const bf16x8*)(vtbase + (size_t)r * SEQLEN + kt * 64 + c8);
        }
        __syncthreads();

        f32x4 s[4];
        #pragma unroll
        for (int t = 0; t < 4; ++t) s[t] = (f32x4){0.f, 0.f, 0.f, 0.f};
        #pragma unroll
        for (int t = 0; t < 4; ++t) {
            bf16x8 kf0 = *(const bf16x8*)&Klds[t * 16 + lr][lg * 8];
            bf16x8 kf1 = *(const bf16x8*)&Klds[t * 16 + lr][32 + lg * 8];
            s[t] = __builtin_amdgcn_mfma_f32_16x16x32_bf16(qfrag0, kf0, s[t], 0, 0, 0);
            s[t] = __builtin_amdgcn_mfma_f32_16x16x32_bf16(qfrag1, kf1, s[t], 0, 0, 0);
        }

        #pragma unroll
        for (int r = 0; r < 4; ++r) {
            float s0 = s[0][r] * scale, s1 = s[1][r] * scale;
            float s2 = s[2][r] * scale, s3 = s[3][r] * scale;
            float mr = fmaxf(fmaxf(s0, s1), fmaxf(s2, s3));
            mr = fmaxf(mr, __shfl_xor(mr, 1));
            mr = fmaxf(mr, __shfl_xor(mr, 2));
            mr = fmaxf(mr, __shfl_xor(mr, 4));
            mr = fmaxf(mr, __shfl_xor(mr, 8));
            const float mnew = fmaxf(m_run[r], mr);
            const float corr = __expf(m_run[r] - mnew);
            m_run[r] = mnew;
            s0 = __expf(s0 - mnew); s1 = __expf(s1 - mnew);
            s2 = __expf(s2 - mnew); s3 = __expf(s3 - mnew);
            float ls = s0 + s1 + s2 + s3;
            ls += __shfl_xor(ls, 1);
            ls += __shfl_xor(ls, 2);
            ls += __shfl_xor(ls, 4);
            ls += __shfl_xor(ls, 8);
            l_run[r] = l_run[r] * corr + ls;
            #pragma unroll
            for (int dt = 0; dt < 4; ++dt) o[dt][r] *= corr;
            const int q = lg * 4 + r;
            Plds[wv][q][ 0 + lr] = __float2bfloat16(s0);
            Plds[wv][q][16 + lr] = __float2bfloat16(s1);
            Plds[wv][q][32 + lr] = __float2bfloat16(s2);
            Plds[wv][q][48 + lr] = __float2bfloat16(s3);
        }

        #pragma unroll
        for (int ks = 0; ks < 2; ++ks) {
            bf16x8 pa = *(const bf16x8*)&Plds[wv][lr][ks * 32 + lg * 8];
            #pragma unroll
            for (int dt = 0; dt < 4; ++dt) {
                bf16x8 vf = *(const bf16x8*)&Vtlds[dt * 16 + lr][ks * 32 + lg * 8];
                o[dt] = __builtin_amdgcn_mfma_f32_16x16x32_bf16(pa, vf, o[dt], 0, 0, 0);
            }
        }
    }

    #pragma unroll
    for (int r = 0; r < 4; ++r) {
        const float inv = 1.f / l_run[r];
        __hip_bfloat16* yr = y
            + ((size_t)b * SEQLEN + qblk * 64 + wv * 16 + lg * 4 + r) * E_DIM + h * HDIM;
        #pragma unroll
        for (int dt = 0; dt < 4; ++dt)
            yr[dt * 16 + lr] = __float2bfloat16(o[dt][r] * inv);
    }
}

extern "C" void kernel_launch(void* const* d_in, const int* in_sizes, int n_in,
                              void* d_out, int out_size, void* d_ws, size_t ws_size,
                              hipStream_t stream)
{
    const float* x    = (const float*)d_in[0];
    const float* win  = (const float*)d_in[1];
    const float* bin  = (const float*)d_in[2];
    const float* wout = (const float*)d_in[3];
    const float* bout = (const float*)d_in[4];
    float* out = (float*)d_out;

    const size_t n_x    = (size_t)BATCHN * SEQLEN * E_DIM;   // 4.19M
    const size_t n_win  = (size_t)QKV_DIM * E_DIM;           // 3.15M
    const size_t n_wout = (size_t)E_DIM * E_DIM;             // 1.05M
    const size_t per_buf = (size_t)BATCHN * NHEADS * SEQLEN * HDIM;

    __hip_bfloat16* xb    = (__hip_bfloat16*)d_ws;
    __hip_bfloat16* winb  = xb + n_x;
    __hip_bfloat16* woutb = winb + n_win;
    __hip_bfloat16* qbuf  = woutb + n_wout;
    __hip_bfloat16* kbuf  = qbuf + per_buf;
    __hip_bfloat16* vtbuf = kbuf + per_buf;
    __hip_bfloat16* yat   = vtbuf + per_buf;

    const int M = BATCHN * SEQLEN;  // 4096
    dim3 blk(256);

    cast_kernel<<<dim3((int)(n_x    / 8 / 256)), blk, 0, stream>>>(x,    xb,    (int)(n_x    / 8));
    cast_kernel<<<dim3((int)(n_win  / 8 / 256)), blk, 0, stream>>>(win,  winb,  (int)(n_win  / 8));
    cast_kernel<<<dim3((int)(n_wout / 8 / 256)), blk, 0, stream>>>(wout, woutb, (int)(n_wout / 8));

    // 1) qkv projection (bf16 MFMA) -> q/k/vT bf16 buffers
    gemm_bf16_kernel<1><<<dim3(QKV_DIM / 128, M / 128), blk, 0, stream>>>(
        xb, winb, bin, nullptr, qbuf, kbuf, vtbuf, M, QKV_DIM, E_DIM);

    // 2) bf16 MFMA flash attention -> yat (bf16)
    attn_mfma_kernel<<<dim3(SEQLEN / 64, NHEADS, BATCHN), blk, 0, stream>>>(
        qbuf, kbuf, vtbuf, yat);

    // 3) out-proj (bf16 MFMA, fp32 out)
    gemm_bf16_kernel<0><<<dim3(E_DIM / 128, M / 128), blk, 0, stream>>>(
        yat, woutb, bout, out, nullptr, nullptr, nullptr, M, E_DIM, E_DIM);
}

// Round 6
// 180.297 us; speedup vs baseline: 15.6652x; 1.2173x over previous
//
#include <hip/hip_runtime.h>
#include <hip/hip_bf16.h>
#include <cstdint>

#define E_DIM   1024
#define NHEADS  16
#define HDIM    64
#define BATCHN  2
#define SEQLEN  2048
#define QKV_DIM 3072

typedef __attribute__((ext_vector_type(8))) short bf16x8;
typedef __attribute__((ext_vector_type(8))) short short8_t;
typedef __attribute__((ext_vector_type(4))) float f32x4;
typedef __attribute__((ext_vector_type(16))) float f32x16;

__device__ __forceinline__ short f2bf_raw(float v) {
    __hip_bfloat16 t = __float2bfloat16(v);
    return *reinterpret_cast<short*>(&t);
}
__device__ __forceinline__ float bf2f(short s) {
    uint32_t u = ((uint32_t)(uint16_t)s) << 16;
    return __builtin_bit_cast(float, u);
}
__device__ __forceinline__ uint32_t pk2(float lo, float hi) {
    uint32_t l = (uint16_t)f2bf_raw(lo);
    uint32_t h = (uint16_t)f2bf_raw(hi);
    return l | (h << 16);
}
// P-pack exchange: operands are always DISTINCT values -> no coalescing hazard.
__device__ __forceinline__ void plswap(uint32_t& a, uint32_t& b) {
    asm volatile("v_permlane32_swap_b32 %0, %1" : "+v"(a), "+v"(b));
}
// cross-half (lane ^ 32) combines via shfl: unambiguous semantics
__device__ __forceinline__ float xmax32(float x) {
    return fmaxf(x, __shfl_xor(x, 32));
}
__device__ __forceinline__ float xsum32(float x) {
    return x + __shfl_xor(x, 32);
}
__device__ __forceinline__ bf16x8 pack4(uint32_t x, uint32_t y, uint32_t z, uint32_t w) {
    union { uint32_t u[4]; bf16x8 v; } t;
    t.u[0] = x; t.u[1] = y; t.u[2] = z; t.u[3] = w;
    return t.v;
}
__device__ __forceinline__ void gload_lds16(const __hip_bfloat16* g, __hip_bfloat16* l) {
    __builtin_amdgcn_global_load_lds(
        (const __attribute__((address_space(1))) uint32_t*)(const void*)g,
        (__attribute__((address_space(3))) uint32_t*)(void*)l,
        16, 0, 0);
}
// XOR swizzle: elem offset within a [row][64] bf16 tile (128B rows)
__device__ __forceinline__ int swz(int row, int col) {
    return (row * 64 + col) ^ ((row & 7) << 3);
}

// ---------------------------------------------------------------------------
// fp32 -> bf16 cast, 8 elems/thread
// ---------------------------------------------------------------------------
__global__ __launch_bounds__(256) void cast_kernel(
    const float* __restrict__ s, __hip_bfloat16* __restrict__ d, int n8)
{
    int i = blockIdx.x * 256 + (int)threadIdx.x;
    if (i >= n8) return;
    const float4* s4 = (const float4*)s;
    float4 a = s4[i * 2];
    float4 b = s4[i * 2 + 1];
    short8_t o;
    o[0] = f2bf_raw(a.x); o[1] = f2bf_raw(a.y);
    o[2] = f2bf_raw(a.z); o[3] = f2bf_raw(a.w);
    o[4] = f2bf_raw(b.x); o[5] = f2bf_raw(b.y);
    o[6] = f2bf_raw(b.z); o[7] = f2bf_raw(b.w);
    *(short8_t*)&d[(size_t)i * 8] = o;
}

// ---------------------------------------------------------------------------
// bf16 MFMA GEMM (unchanged): C = A @ W^T + bias
// ---------------------------------------------------------------------------
template<int EPI>
__global__ __launch_bounds__(256) void gemm_bf16_kernel(
    const __hip_bfloat16* __restrict__ A, const __hip_bfloat16* __restrict__ W,
    const float* __restrict__ bias, float* __restrict__ C,
    __hip_bfloat16* __restrict__ qbuf, __hip_bfloat16* __restrict__ kbuf,
    __hip_bfloat16* __restrict__ vtbuf, int M, int N, int K)
{
    __shared__ __hip_bfloat16 As[128 * 64];
    __shared__ __hip_bfloat16 Ws[128 * 64];

    const int tid  = (int)threadIdx.x;
    const int wv   = tid >> 6;
    const int lane = tid & 63;
    const int lr   = lane & 15;
    const int lg   = lane >> 4;
    const int wr   = wv >> 1;
    const int wc   = wv & 1;

    const int bm = blockIdx.y * 128;
    const int bn = blockIdx.x * 128;

    const int srow = lane >> 3;
    const int sk   = (lane & 7) * 8;

    f32x4 acc[4][4];
    #pragma unroll
    for (int m = 0; m < 4; ++m)
        #pragma unroll
        for (int n = 0; n < 4; ++n)
            acc[m][n] = (f32x4){0.f, 0.f, 0.f, 0.f};

    for (int k0 = 0; k0 < K; k0 += 64) {
        __syncthreads();
        #pragma unroll
        for (int i = 0; i < 4; ++i) {
            const int r = i * 32 + wv * 8;
            gload_lds16(A + (size_t)(bm + r + srow) * K + k0 + sk, &As[r * 64]);
            gload_lds16(W + (size_t)(bn + r + srow) * K + k0 + sk, &Ws[r * 64]);
        }
        __syncthreads();
        #pragma unroll
        for (int ks = 0; ks < 2; ++ks) {
            bf16x8 af[4], wf[4];
            #pragma unroll
            for (int m = 0; m < 4; ++m)
                af[m] = *(const bf16x8*)&As[(wr * 64 + m * 16 + lr) * 64 + ks * 32 + lg * 8];
            #pragma unroll
            for (int n = 0; n < 4; ++n)
                wf[n] = *(const bf16x8*)&Ws[(wc * 64 + n * 16 + lr) * 64 + ks * 32 + lg * 8];
            #pragma unroll
            for (int m = 0; m < 4; ++m)
                #pragma unroll
                for (int n = 0; n < 4; ++n)
                    acc[m][n] = __builtin_amdgcn_mfma_f32_16x16x32_bf16(
                        af[m], wf[n], acc[m][n], 0, 0, 0);
        }
    }

    if (EPI == 0) {
        #pragma unroll
        for (int n = 0; n < 4; ++n) {
            const int col = bn + wc * 64 + n * 16 + lr;
            const float bv = bias[col];
            #pragma unroll
            for (int m = 0; m < 4; ++m) {
                const int row0 = bm + wr * 64 + m * 16 + lg * 4;
                #pragma unroll
                for (int rr = 0; rr < 4; ++rr)
                    C[(size_t)(row0 + rr) * N + col] = acc[m][n][rr] + bv;
            }
        }
    } else {
        #pragma unroll
        for (int n = 0; n < 4; ++n) {
            const int col = bn + wc * 64 + n * 16 + lr;
            const float bv = bias[col];
            const int region = col >> 10;
            const int h = (col >> 6) & 15;
            const int d = col & 63;
            #pragma unroll
            for (int m = 0; m < 4; ++m) {
                #pragma unroll
                for (int rr = 0; rr < 4; ++rr) {
                    const int row = bm + wr * 64 + m * 16 + lg * 4 + rr;
                    const int bb = row >> 11;
                    const int s  = row & 2047;
                    const float v = acc[m][n][rr] + bv;
                    if (region == 2) {
                        vtbuf[((size_t)(bb * NHEADS + h) * HDIM + d) * SEQLEN + s] =
                            __float2bfloat16(v);
                    } else {
                        ((region == 0) ? qbuf : kbuf)
                            [((size_t)(bb * NHEADS + h) * SEQLEN + s) * HDIM + d] =
                            __float2bfloat16(v);
                    }
                }
            }
        }
    }
}

// ---------------------------------------------------------------------------
// Flash attention, swapped-operand 32x32x16 MFMA, in-register softmax.
// Grid: (S/128, H, B). Block: 256 = 4 waves; wave w owns q rows w*32..w*32+31.
// Lane holds S^T col q = lane&31; keys split across hi = lane>>5 halves.
// ---------------------------------------------------------------------------
__global__ __launch_bounds__(256) void attn32_kernel(
    const __hip_bfloat16* __restrict__ qbuf, const __hip_bfloat16* __restrict__ kbuf,
    const __hip_bfloat16* __restrict__ vtbuf, __hip_bfloat16* __restrict__ y)
{
    __shared__ __hip_bfloat16 smem[9216];  // K:[0,4096) V:[4096,8192); epilogue reuses [0,9216)

    const int qblk = blockIdx.x;
    const int h = blockIdx.y;
    const int b = blockIdx.z;
    const int bh = b * NHEADS + h;
    const int tid = (int)threadIdx.x;
    const int wv  = tid >> 6;
    const int lane = tid & 63;
    const int l31 = lane & 31;
    const int hi  = lane >> 5;
    const float QSCALE = 0.18033688f;  // 0.125 * log2(e)

    // Q fragments (B-operand): lane holds Q[q=l31][dk*16 + hi*8 + j], pre-scaled
    const __hip_bfloat16* qrow =
        qbuf + ((size_t)bh * SEQLEN + qblk * 128 + wv * 32 + l31) * HDIM;
    bf16x8 qf[4];
    #pragma unroll
    for (int dk = 0; dk < 4; ++dk) {
        bf16x8 q = *(const bf16x8*)(qrow + dk * 16 + hi * 8);
        union { uint32_t u[4]; bf16x8 v; } t;
        #pragma unroll
        for (int p = 0; p < 4; ++p)
            t.u[p] = pk2(bf2f(q[p * 2]) * QSCALE, bf2f(q[p * 2 + 1]) * QSCALE);
        qf[dk] = t.v;
    }

    f32x16 o0, o1;
    #pragma unroll
    for (int i = 0; i < 16; ++i) { o0[i] = 0.f; o1[i] = 0.f; }
    float m_run = -1e30f, l_run = 0.f;

    const __hip_bfloat16* kbase  = kbuf  + (size_t)bh * SEQLEN * HDIM;
    const __hip_bfloat16* vtbase = vtbuf + (size_t)bh * HDIM * SEQLEN;

    for (int kt = 0; kt < SEQLEN / 64; ++kt) {
        __syncthreads();
        // stage K[64][64] and V^T[64][64], XOR-swizzled rows
        #pragma unroll
        for (int p = 0; p < 2; ++p) {
            const int c = tid + p * 256;
            const int r = c >> 3, c8 = (c & 7) * 8;
            bf16x8 kv = *(const bf16x8*)(kbase + (size_t)(kt * 64 + r) * HDIM + c8);
            *(bf16x8*)&smem[swz(r, c8)] = kv;
            bf16x8 vv = *(const bf16x8*)(vtbase + (size_t)r * SEQLEN + kt * 64 + c8);
            *(bf16x8*)&smem[4096 + swz(r, c8)] = vv;
        }
        __syncthreads();

        // S^T[key][q] = K . Q^T  (two 32-key blocks, K=64 over 4 slices)
        f32x16 s0, s1;
        #pragma unroll
        for (int i = 0; i < 16; ++i) { s0[i] = 0.f; s1[i] = 0.f; }
        #pragma unroll
        for (int dk = 0; dk < 4; ++dk) {
            bf16x8 kf0 = *(const bf16x8*)&smem[swz(l31,      dk * 16 + hi * 8)];
            bf16x8 kf1 = *(const bf16x8*)&smem[swz(32 + l31, dk * 16 + hi * 8)];
            s0 = __builtin_amdgcn_mfma_f32_32x32x16_bf16(kf0, qf[dk], s0, 0, 0, 0);
            s1 = __builtin_amdgcn_mfma_f32_32x32x16_bf16(kf1, qf[dk], s1, 0, 0, 0);
        }

        // online softmax (exp2 domain): lane-local max/sum + cross-half shfl
        float mloc = s0[0];
        #pragma unroll
        for (int i = 1; i < 16; ++i) mloc = fmaxf(mloc, s0[i]);
        #pragma unroll
        for (int i = 0; i < 16; ++i) mloc = fmaxf(mloc, s1[i]);
        mloc = xmax32(mloc);
        const float mnew = fmaxf(m_run, mloc);
        const float corr = exp2f(m_run - mnew);
        m_run = mnew;

        float p0[16], p1[16];
        float ls = 0.f;
        #pragma unroll
        for (int i = 0; i < 16; ++i) { p0[i] = exp2f(s0[i] - mnew); ls += p0[i]; }
        #pragma unroll
        for (int i = 0; i < 16; ++i) { p1[i] = exp2f(s1[i] - mnew); ls += p1[i]; }
        ls = xsum32(ls);
        l_run = l_run * corr + ls;
        #pragma unroll
        for (int i = 0; i < 16; ++i) { o0[i] *= corr; o1[i] *= corr; }

        // P -> bf16 B-fragments via cvt_pk + permlane32_swap (distinct operands)
        uint32_t a0 = pk2(p0[0],  p0[1]),  b0 = pk2(p0[4],  p0[5]);  plswap(a0, b0);
        uint32_t a1 = pk2(p0[2],  p0[3]),  b1 = pk2(p0[6],  p0[7]);  plswap(a1, b1);
        uint32_t a2 = pk2(p0[8],  p0[9]),  b2 = pk2(p0[12], p0[13]); plswap(a2, b2);
        uint32_t a3 = pk2(p0[10], p0[11]), b3 = pk2(p0[14], p0[15]); plswap(a3, b3);
        uint32_t a4 = pk2(p1[0],  p1[1]),  b4 = pk2(p1[4],  p1[5]);  plswap(a4, b4);
        uint32_t a5 = pk2(p1[2],  p1[3]),  b5 = pk2(p1[6],  p1[7]);  plswap(a5, b5);
        uint32_t a6 = pk2(p1[8],  p1[9]),  b6 = pk2(p1[12], p1[13]); plswap(a6, b6);
        uint32_t a7 = pk2(p1[10], p1[11]), b7 = pk2(p1[14], p1[15]); plswap(a7, b7);
        bf16x8 pf0 = pack4(a0, a1, b0, b1);
        bf16x8 pf1 = pack4(a2, a3, b2, b3);
        bf16x8 pf2 = pack4(a4, a5, b4, b5);
        bf16x8 pf3 = pack4(a6, a7, b6, b7);

        // O^T += V^T . P^T  (two 32-d blocks, 4 key slices)
        #define PV_STEP(ks, pf)                                                        \
        {                                                                              \
            bf16x8 vf0 = *(const bf16x8*)&smem[4096 + swz(l31,      ks * 16 + hi * 8)];\
            bf16x8 vf1 = *(const bf16x8*)&smem[4096 + swz(32 + l31, ks * 16 + hi * 8)];\
            o0 = __builtin_amdgcn_mfma_f32_32x32x16_bf16(vf0, pf, o0, 0, 0, 0);        \
            o1 = __builtin_amdgcn_mfma_f32_32x32x16_bf16(vf1, pf, o1, 0, 0, 0);        \
        }
        PV_STEP(0, pf0)
        PV_STEP(1, pf1)
        PV_STEP(2, pf2)
        PV_STEP(3, pf3)
        #undef PV_STEP
    }

    // epilogue: transpose O^T -> [q][d] through LDS, coalesced bf16 stores
    const float inv = 1.f / l_run;
    const int qrow_l = wv * 32 + l31;
    __syncthreads();
    #pragma unroll
    for (int od = 0; od < 2; ++od) {
        #pragma unroll
        for (int r = 0; r < 16; ++r) {
            const int d = (r & 3) + 8 * (r >> 2) + 4 * hi + 32 * od;
            const float v = (od ? o1[r] : o0[r]) * inv;
            smem[qrow_l * 72 + d] = __float2bfloat16(v);
        }
    }
    __syncthreads();
    #pragma unroll
    for (int p = 0; p < 4; ++p) {
        const int c = tid + p * 256;         // 1024 chunks: 128 rows x 8
        const int row = c >> 3, c8 = (c & 7) * 8;
        bf16x8 v = *(const bf16x8*)&smem[row * 72 + c8];
        __hip_bfloat16* dst = y
            + ((size_t)b * SEQLEN + qblk * 128 + row) * E_DIM + h * HDIM + c8;
        *(bf16x8*)dst = v;
    }
}

extern "C" void kernel_launch(void* const* d_in, const int* in_sizes, int n_in,
                              void* d_out, int out_size, void* d_ws, size_t ws_size,
                              hipStream_t stream)
{
    const float* x    = (const float*)d_in[0];
    const float* win  = (const float*)d_in[1];
    const float* bin  = (const float*)d_in[2];
    const float* wout = (const float*)d_in[3];
    const float* bout = (const float*)d_in[4];
    float* out = (float*)d_out;

    const size_t n_x    = (size_t)BATCHN * SEQLEN * E_DIM;
    const size_t n_win  = (size_t)QKV_DIM * E_DIM;
    const size_t n_wout = (size_t)E_DIM * E_DIM;
    const size_t per_buf = (size_t)BATCHN * NHEADS * SEQLEN * HDIM;

    __hip_bfloat16* xb    = (__hip_bfloat16*)d_ws;
    __hip_bfloat16* winb  = xb + n_x;
    __hip_bfloat16* woutb = winb + n_win;
    __hip_bfloat16* qbuf  = woutb + n_wout;
    __hip_bfloat16* kbuf  = qbuf + per_buf;
    __hip_bfloat16* vtbuf = kbuf + per_buf;
    __hip_bfloat16* yat   = vtbuf + per_buf;

    const int M = BATCHN * SEQLEN;  // 4096
    dim3 blk(256);

    cast_kernel<<<dim3((int)(n_x    / 8 / 256)), blk, 0, stream>>>(x,    xb,    (int)(n_x    / 8));
    cast_kernel<<<dim3((int)(n_win  / 8 / 256)), blk, 0, stream>>>(win,  winb,  (int)(n_win  / 8));
    cast_kernel<<<dim3((int)(n_wout / 8 / 256)), blk, 0, stream>>>(wout, woutb, (int)(n_wout / 8));

    gemm_bf16_kernel<1><<<dim3(QKV_DIM / 128, M / 128), blk, 0, stream>>>(
        xb, winb, bin, nullptr, qbuf, kbuf, vtbuf, M, QKV_DIM, E_DIM);

    attn32_kernel<<<dim3(SEQLEN / 128, NHEADS, BATCHN), blk, 0, stream>>>(
        qbuf, kbuf, vtbuf, yat);

    gemm_bf16_kernel<0><<<dim3(E_DIM / 128, M / 128), blk, 0, stream>>>(
        yat, woutb, bout, out, nullptr, nullptr, nullptr, M, E_DIM, E_DIM);
}